// Round 2
// baseline (805.206 us; speedup 1.0000x reference)
//
#include <hip/hip_runtime.h>
#include <hip/hip_bf16.h>

#define NAGENT 32768
#define MAXN   16
#define FNBR   32
#define FAGT   32
#define FHOP   8
#define HD     128
#define NPOW   4
#define QCOLS  (MAXN * NPOW + 1)   // 65
#define QN     (NAGENT * QCOLS)

struct TagF32 { static constexpr bool value = false; };
struct TagBF16 { static constexpr bool value = true; };

template <bool BF16>
__device__ __forceinline__ float ld(const void* p, int i) {
    if constexpr (BF16) return __bfloat162float(((const __hip_bfloat16*)p)[i]);
    else return ((const float*)p)[i];
}
template <bool BF16>
__device__ __forceinline__ void st(void* p, int i, float v) {
    if constexpr (BF16) ((__hip_bfloat16*)p)[i] = __float2bfloat16(v);
    else ((float*)p)[i] = v;
}

__device__ __forceinline__ float dot4(float4 c, float w0, float w1, float w2, float w3, float acc) {
    acc = fmaf(c.x, w0, acc);
    acc = fmaf(c.y, w1, acc);
    acc = fmaf(c.z, w2, acc);
    acc = fmaf(c.w, w3, acc);
    return acc;
}

__global__ __launch_bounds__(128) void fused_gnn(
    const void* __restrict__ feat_nbr,
    const void* __restrict__ feat_agent,
    const void* __restrict__ edge_feat,
    const void* __restrict__ h_in,
    const void* __restrict__ W_msg, const void* __restrict__ b_msg,
    const void* __restrict__ W_upd, const void* __restrict__ b_upd,
    const void* __restrict__ W_x,  const void* __restrict__ W_h,
    const void* __restrict__ b_ih, const void* __restrict__ b_hh,
    const void* __restrict__ W_e1, const void* __restrict__ b_e1,
    const void* __restrict__ W_e2, const void* __restrict__ b_e2,
    const void* __restrict__ W_a,  const void* __restrict__ b_a,
    const int* __restrict__ src_idx,
    void* __restrict__ out)
{
    const int a = blockIdx.x;
    const int t = threadIdx.x;
    const int be = a * MAXN;   // base edge for this agent (edges grouped by dst)

    __shared__ __align__(16) float fn[MAXN][FNBR];
    __shared__ __align__(16) float ef[MAXN][FHOP];
    __shared__ __align__(16) float fa[FAGT];
    __shared__ __align__(16) float hr[HD];
    __shared__ __align__(16) float aggs[HD];
    __shared__ __align__(16) float xs[HD];
    __shared__ __align__(16) float hnew[HD];
    __shared__ __align__(16) float ze[MAXN][HD + 4];   // stride 132: breaks 16-way bank conflict in e2
    __shared__ float red[HD];
    __shared__ int srcs[MAXN];
    __shared__ int dflag;

    // ---- runtime input-dtype detector ----
    // If inputs are bf16, W_msg's even-index elements are real N(0,1/40) weights
    // (|x| < 1, bf16 exponent <= 126). If inputs are f32, those same 2-byte slots
    // are the LOW mantissa halves of floats: ~uniform random bits, so among 128
    // samples some bf16-decoded exponent >= 134 (|x| >= 128) with P ~ 1-1e-37.
    if (t == 0) dflag = 0;
    __syncthreads();
    {
        const unsigned short* raw = (const unsigned short*)W_msg;
        unsigned short r = raw[2 * t];                 // even bf16 indices 0..254
        unsigned ex = (r >> 7) & 0xFFu;
        if (ex >= 134u) atomicOr(&dflag, 1);
    }
    __syncthreads();
    const bool is_f32 = (dflag != 0);

    auto run = [&](auto tag) {
        constexpr bool BF16 = decltype(tag)::value;

        // ---------------- load inputs ----------------
        if (t < MAXN) srcs[t] = src_idx[be + t];
        if (t < FAGT) fa[t] = ld<BF16>(feat_agent, a * FAGT + t);
        hr[t] = ld<BF16>(h_in, a * HD + t);
        {   // 16 edges x 8 feats = 128 elements, one per thread, coalesced
            int e = t >> 3, k = t & 7;
            ef[e][k] = ld<BF16>(edge_feat, be * FHOP + t);
        }
        __syncthreads();
        if constexpr (!BF16) {
            // gather rows as float4: 16 rows x 8 float4 = 128, one per thread
            int e = t >> 3, j = t & 7;
            ((float4*)&fn[e][0])[j] = ((const float4*)feat_nbr)[srcs[e] * (FNBR / 4) + j];
        } else {
            #pragma unroll
            for (int i = 0; i < 4; ++i) {   // 16 edges x 32 feats = 512 elements (gather)
                int idx = t + i * 128;
                int e = idx >> 5, k = idx & 31;
                fn[e][k] = ld<BF16>(feat_nbr, srcs[e] * FNBR + k);
            }
        }
        __syncthreads();

        // ---------------- stage 1: edge messages + sum-aggregate ----------------
        float acc[MAXN];
        #pragma unroll
        for (int e = 0; e < MAXN; ++e) acc[e] = 0.f;
        #pragma unroll
        for (int kc = 0; kc < FNBR; kc += 4) {
            float w0 = ld<BF16>(W_msg, (kc + 0) * HD + t);
            float w1 = ld<BF16>(W_msg, (kc + 1) * HD + t);
            float w2 = ld<BF16>(W_msg, (kc + 2) * HD + t);
            float w3 = ld<BF16>(W_msg, (kc + 3) * HD + t);
            #pragma unroll
            for (int e = 0; e < MAXN; ++e)
                acc[e] = dot4(*(const float4*)&fn[e][kc], w0, w1, w2, w3, acc[e]);
        }
        #pragma unroll
        for (int kc = 0; kc < FHOP; kc += 4) {
            float w0 = ld<BF16>(W_msg, (FNBR + kc + 0) * HD + t);
            float w1 = ld<BF16>(W_msg, (FNBR + kc + 1) * HD + t);
            float w2 = ld<BF16>(W_msg, (FNBR + kc + 2) * HD + t);
            float w3 = ld<BF16>(W_msg, (FNBR + kc + 3) * HD + t);
            #pragma unroll
            for (int e = 0; e < MAXN; ++e)
                acc[e] = dot4(*(const float4*)&ef[e][kc], w0, w1, w2, w3, acc[e]);
        }
        {
            float bm = ld<BF16>(b_msg, t);
            float aggt = 0.f;
            #pragma unroll
            for (int e = 0; e < MAXN; ++e) aggt += fmaxf(acc[e] + bm, 0.f);
            aggs[t] = aggt;
        }
        __syncthreads();

        // ---------------- stage 2: node update ----------------
        float xt;
        {
            float acc2 = ld<BF16>(b_upd, t);
            #pragma unroll
            for (int kc = 0; kc < HD; kc += 4) {
                float w0 = ld<BF16>(W_upd, (kc + 0) * HD + t);
                float w1 = ld<BF16>(W_upd, (kc + 1) * HD + t);
                float w2 = ld<BF16>(W_upd, (kc + 2) * HD + t);
                float w3 = ld<BF16>(W_upd, (kc + 3) * HD + t);
                acc2 = dot4(*(const float4*)&aggs[kc], w0, w1, w2, w3, acc2);
            }
            #pragma unroll
            for (int kc = 0; kc < FAGT; kc += 4) {
                float w0 = ld<BF16>(W_upd, (HD + kc + 0) * HD + t);
                float w1 = ld<BF16>(W_upd, (HD + kc + 1) * HD + t);
                float w2 = ld<BF16>(W_upd, (HD + kc + 2) * HD + t);
                float w3 = ld<BF16>(W_upd, (HD + kc + 3) * HD + t);
                acc2 = dot4(*(const float4*)&fa[kc], w0, w1, w2, w3, acc2);
            }
            xt = fmaxf(acc2, 0.f);
            xs[t] = xt;
        }
        __syncthreads();

        // ---------------- stage 3: GRU cell ----------------
        float hn_t;
        {
            float gi0 = ld<BF16>(b_ih, t), gi1 = ld<BF16>(b_ih, HD + t), gi2 = ld<BF16>(b_ih, 2 * HD + t);
            float gh0 = ld<BF16>(b_hh, t), gh1 = ld<BF16>(b_hh, HD + t), gh2 = ld<BF16>(b_hh, 2 * HD + t);
            for (int kc = 0; kc < HD; kc += 4) {
                float4 xv = *(const float4*)&xs[kc];
                float4 hv = *(const float4*)&hr[kc];
                const float xa[4] = {xv.x, xv.y, xv.z, xv.w};
                const float ha[4] = {hv.x, hv.y, hv.z, hv.w};
                #pragma unroll
                for (int j = 0; j < 4; ++j) {
                    int rowx = (kc + j) * (3 * HD);
                    gi0 = fmaf(xa[j], ld<BF16>(W_x, rowx + t), gi0);
                    gi1 = fmaf(xa[j], ld<BF16>(W_x, rowx + HD + t), gi1);
                    gi2 = fmaf(xa[j], ld<BF16>(W_x, rowx + 2 * HD + t), gi2);
                    gh0 = fmaf(ha[j], ld<BF16>(W_h, rowx + t), gh0);
                    gh1 = fmaf(ha[j], ld<BF16>(W_h, rowx + HD + t), gh1);
                    gh2 = fmaf(ha[j], ld<BF16>(W_h, rowx + 2 * HD + t), gh2);
                }
            }
            float rg = 1.f / (1.f + __expf(-(gi0 + gh0)));
            float zg = 1.f / (1.f + __expf(-(gi1 + gh1)));
            float ng = tanhf(gi2 + rg * gh2);
            hn_t = (1.f - zg) * ng + zg * hr[t];
            hnew[t] = hn_t;
            st<BF16>(out, QN + a * HD + t, hn_t);   // second output: h_new
        }
        __syncthreads();

        // ---------------- stage 4: e1 edge MLP (h_new part hoisted across edges) ----------------
        {
            float hacc = 0.f;  // dot(h_new, W_e1[32:160, t]) — identical for all 16 edges
            #pragma unroll
            for (int kc = 0; kc < HD; kc += 4) {
                float w0 = ld<BF16>(W_e1, (FNBR + kc + 0) * HD + t);
                float w1 = ld<BF16>(W_e1, (FNBR + kc + 1) * HD + t);
                float w2 = ld<BF16>(W_e1, (FNBR + kc + 2) * HD + t);
                float w3 = ld<BF16>(W_e1, (FNBR + kc + 3) * HD + t);
                hacc = dot4(*(const float4*)&hnew[kc], w0, w1, w2, w3, hacc);
            }
            float acc3[MAXN];
            #pragma unroll
            for (int e = 0; e < MAXN; ++e) acc3[e] = hacc;
            #pragma unroll
            for (int kc = 0; kc < FNBR; kc += 4) {
                float w0 = ld<BF16>(W_e1, (kc + 0) * HD + t);
                float w1 = ld<BF16>(W_e1, (kc + 1) * HD + t);
                float w2 = ld<BF16>(W_e1, (kc + 2) * HD + t);
                float w3 = ld<BF16>(W_e1, (kc + 3) * HD + t);
                #pragma unroll
                for (int e = 0; e < MAXN; ++e)
                    acc3[e] = dot4(*(const float4*)&fn[e][kc], w0, w1, w2, w3, acc3[e]);
            }
            #pragma unroll
            for (int kc = 0; kc < FHOP; kc += 4) {
                float w0 = ld<BF16>(W_e1, (FNBR + HD + kc + 0) * HD + t);
                float w1 = ld<BF16>(W_e1, (FNBR + HD + kc + 1) * HD + t);
                float w2 = ld<BF16>(W_e1, (FNBR + HD + kc + 2) * HD + t);
                float w3 = ld<BF16>(W_e1, (FNBR + HD + kc + 3) * HD + t);
                #pragma unroll
                for (int e = 0; e < MAXN; ++e)
                    acc3[e] = dot4(*(const float4*)&ef[e][kc], w0, w1, w2, w3, acc3[e]);
            }
            float be1 = ld<BF16>(b_e1, t);
            float agg2t = 0.f;
            #pragma unroll
            for (int e = 0; e < MAXN; ++e) {
                float z = fmaxf(acc3[e] + be1, 0.f);
                ze[e][t] = z;
                agg2t += z;
            }
            // agent head partial: agg2[t]*W_a[t] + h_new[t]*W_a[128+t]
            red[t] = fmaf(agg2t, ld<BF16>(W_a, t), hn_t * ld<BF16>(W_a, HD + t));
        }
        __syncthreads();

        // ---------------- stage 5: e2 per-edge q-values + agent scalar ----------------
        if (t < 64) {
            int e = t >> 2, p = t & 3;   // out column = e*4+p == t (matches reshape)
            float acc4 = ld<BF16>(b_e2, p);
            for (int kc = 0; kc < HD; kc += 4) {
                float4 zv = *(const float4*)&ze[e][kc];
                acc4 = fmaf(zv.x, ld<BF16>(W_e2, (kc + 0) * NPOW + p), acc4);
                acc4 = fmaf(zv.y, ld<BF16>(W_e2, (kc + 1) * NPOW + p), acc4);
                acc4 = fmaf(zv.z, ld<BF16>(W_e2, (kc + 2) * NPOW + p), acc4);
                acc4 = fmaf(zv.w, ld<BF16>(W_e2, (kc + 3) * NPOW + p), acc4);
            }
            st<BF16>(out, a * QCOLS + t, acc4);
            float v = red[t] + red[t + 64];
            #pragma unroll
            for (int off = 32; off > 0; off >>= 1) v += __shfl_down(v, off);
            if (t == 0) st<BF16>(out, a * QCOLS + 64, v + ld<BF16>(b_a, 0));
        }
    };

    if (is_f32) run(TagF32{});
    else        run(TagBF16{});
}

extern "C" void kernel_launch(void* const* d_in, const int* in_sizes, int n_in,
                              void* d_out, int out_size, void* d_ws, size_t ws_size,
                              hipStream_t stream) {
    const void* feat_nbr   = d_in[0];
    const void* feat_agent = d_in[1];
    const void* edge_feat  = d_in[2];
    const void* h_in       = d_in[3];
    const void* W_msg = d_in[4];
    const void* b_msg = d_in[5];
    const void* W_upd = d_in[6];
    const void* b_upd = d_in[7];
    const void* W_x   = d_in[8];
    const void* W_h   = d_in[9];
    const void* b_ih  = d_in[10];
    const void* b_hh  = d_in[11];
    const void* W_e1  = d_in[12];
    const void* b_e1  = d_in[13];
    const void* W_e2  = d_in[14];
    const void* b_e2  = d_in[15];
    const void* W_a   = d_in[16];
    const void* b_a   = d_in[17];
    const int* src_idx = (const int*)d_in[18];
    // d_in[19] = dst_idx: unused — edges are grouped by dst with fixed degree 16,
    // so edge block [16a, 16a+16) belongs to agent a by construction.

    fused_gnn<<<NAGENT, 128, 0, stream>>>(
        feat_nbr, feat_agent, edge_feat, h_in,
        W_msg, b_msg, W_upd, b_upd,
        W_x, W_h, b_ih, b_hh,
        W_e1, b_e1, W_e2, b_e2, W_a, b_a,
        src_idx, d_out);
}

// Round 3
// 638.564 us; speedup vs baseline: 1.2610x; 1.2610x over previous
//
#include <hip/hip_runtime.h>

#define NAGENT 32768
#define MAXN   16
#define FNBR   32
#define FAGT   32
#define FHOP   8
#define HD     128
#define NPOW   4
#define QCOLS  65                 // MAXN*NPOW + 1
#define QN     (NAGENT * QCOLS)
#define AG     4                  // agents per block
#define EPB    (AG * MAXN)        // 64 edges per block

__device__ __forceinline__ float dot4w(float4 v, const float* w, float acc) {
    acc = fmaf(v.x, w[0], acc); acc = fmaf(v.y, w[1], acc);
    acc = fmaf(v.z, w[2], acc); acc = fmaf(v.w, w[3], acc);
    return acc;
}
__device__ __forceinline__ float dot8w(float4 v0, float4 v1, const float* w, float acc) {
    acc = dot4w(v0, w, acc);
    acc = dot4w(v1, w + 4, acc);
    return acc;
}

// dtype note: round-2 counters proved f32 I/O (WRITE_SIZE 25.6MB = 6.29M elems * 4B),
// so the runtime bf16/f32 detector is removed.
__global__ __launch_bounds__(128) void fused_gnn(
    const float* __restrict__ feat_nbr, const float* __restrict__ feat_agent,
    const float* __restrict__ edge_feat, const float* __restrict__ h_in,
    const float* __restrict__ W_msg, const float* __restrict__ b_msg,
    const float* __restrict__ W_upd, const float* __restrict__ b_upd,
    const float* __restrict__ W_x,  const float* __restrict__ W_h,
    const float* __restrict__ b_ih, const float* __restrict__ b_hh,
    const float* __restrict__ W_e1, const float* __restrict__ b_e1,
    const float* __restrict__ W_e2, const float* __restrict__ b_e2,
    const float* __restrict__ W_a,  const float* __restrict__ b_a,
    const int* __restrict__ src_idx, float* __restrict__ out)
{
    const int t  = threadIdx.x;        // t = output channel (0..127)
    const int a0 = blockIdx.x * AG;    // first agent of this block
    const int be = a0 * MAXN;          // first edge (edges grouped by dst)

    __shared__ __align__(16) float fn[EPB][FNBR];     // 8 KB  gathered nbr feats
    __shared__ __align__(16) float ef[EPB][FHOP];     // 2 KB  edge feats
    __shared__ __align__(16) float fa[AG][FAGT];      // 0.5 KB
    __shared__ __align__(16) float hrs[AG][HD];       // 2 KB  h_in
    __shared__ __align__(16) float aggs[AG][HD];      // 2 KB
    __shared__ __align__(16) float xs[AG][HD];        // 2 KB
    __shared__ __align__(16) float hnew[AG][HD];      // 2 KB
    __shared__ __align__(16) float ze[MAXN][HD + 4];  // 8.25 KB, stride 132 breaks e2 conflicts
    __shared__ __align__(16) float w2s[HD * NPOW];    // 2 KB  W_e2 copy
    __shared__ float red[HD];
    __shared__ int srcs[EPB];

    // ---------------- stage inputs (all coalesced float4 where contiguous) ----
    if (t < EPB) srcs[t] = src_idx[be + t];
    fa[t >> 5][t & 31] = feat_agent[a0 * FAGT + t];                       // 128 contiguous
    ((float4*)&hrs[0][0])[t] = ((const float4*)(h_in + (size_t)a0 * HD))[t];      // 512 floats
    ((float4*)&ef[0][0])[t] = ((const float4*)(edge_feat + (size_t)be * FHOP))[t];// 512 floats
    ((float4*)w2s)[t] = ((const float4*)W_e2)[t];                          // 512 floats
    __syncthreads();
    #pragma unroll
    for (int i = 0; i < 4; ++i) {      // gather 64 nbr rows x 8 float4
        int idx = t + i * 128;
        int row = idx >> 3, j = idx & 7;
        ((float4*)&fn[row][0])[j] = ((const float4*)feat_nbr)[(size_t)srcs[row] * (FNBR / 4) + j];
    }
    __syncthreads();

    // ---------------- stage 1: edge messages + aggregate ---------------------
    // weights held in 40 regs for the whole block (loaded ONCE, reused 64 edges)
    {
        float wm[FNBR + FHOP];
        #pragma unroll
        for (int k = 0; k < FNBR; ++k) wm[k] = W_msg[k * HD + t];
        #pragma unroll
        for (int k = 0; k < FHOP; ++k) wm[FNBR + k] = W_msg[(FNBR + k) * HD + t];
        const float bm = b_msg[t];
        float agg[AG];
        #pragma unroll
        for (int a = 0; a < AG; ++a) agg[a] = 0.f;
        #pragma unroll 2
        for (int e = 0; e < EPB; ++e) {
            const float4* fnv = (const float4*)&fn[e][0];
            const float4* efv = (const float4*)&ef[e][0];
            float p0 = bm, p1 = 0.f;   // two chains for ILP
            p0 = dot8w(fnv[0], fnv[1], &wm[0],  p0);
            p1 = dot8w(fnv[2], fnv[3], &wm[8],  p1);
            p0 = dot8w(fnv[4], fnv[5], &wm[16], p0);
            p1 = dot8w(fnv[6], fnv[7], &wm[24], p1);
            p0 = dot4w(efv[0], &wm[32], p0);
            p1 = dot4w(efv[1], &wm[36], p1);
            agg[e >> 4] += fmaxf(p0 + p1, 0.f);
        }
        #pragma unroll
        for (int a = 0; a < AG; ++a) aggs[a][t] = agg[a];
    }
    __syncthreads();

    // ---------------- stage 2: node update -----------------------------------
    // K-chunk 8: weights loaded once per block, AG persistent accumulators
    {
        float xv[AG];
        {
            const float bu = b_upd[t];
            #pragma unroll
            for (int a = 0; a < AG; ++a) xv[a] = bu;
        }
        for (int kc = 0; kc < HD; kc += 8) {
            float w[8];
            #pragma unroll
            for (int j = 0; j < 8; ++j) w[j] = W_upd[(kc + j) * HD + t];
            #pragma unroll
            for (int a = 0; a < AG; ++a)
                xv[a] = dot8w(*(const float4*)&aggs[a][kc], *(const float4*)&aggs[a][kc + 4], w, xv[a]);
        }
        #pragma unroll
        for (int kc = 0; kc < FAGT; kc += 8) {
            float w[8];
            #pragma unroll
            for (int j = 0; j < 8; ++j) w[j] = W_upd[(HD + kc + j) * HD + t];
            #pragma unroll
            for (int a = 0; a < AG; ++a)
                xv[a] = dot8w(*(const float4*)&fa[a][kc], *(const float4*)&fa[a][kc + 4], w, xv[a]);
        }
        #pragma unroll
        for (int a = 0; a < AG; ++a) xs[a][t] = fmaxf(xv[a], 0.f);
    }
    __syncthreads();

    // ---------------- stage 3: GRU cell --------------------------------------
    float hnreg[AG];
    {
        float gi0[AG], gi1[AG], gi2[AG], gh0[AG], gh1[AG], gh2[AG];
        {
            const float bi0 = b_ih[t], bi1 = b_ih[HD + t], bi2 = b_ih[2 * HD + t];
            const float bh0 = b_hh[t], bh1 = b_hh[HD + t], bh2 = b_hh[2 * HD + t];
            #pragma unroll
            for (int a = 0; a < AG; ++a) {
                gi0[a] = bi0; gi1[a] = bi1; gi2[a] = bi2;
                gh0[a] = bh0; gh1[a] = bh1; gh2[a] = bh2;
            }
        }
        for (int kc = 0; kc < HD; kc += 8) {       // gi = x @ W_x
            float w0[8], w1[8], w2[8];
            #pragma unroll
            for (int j = 0; j < 8; ++j) {
                const float* r = W_x + (size_t)(kc + j) * (3 * HD);
                w0[j] = r[t]; w1[j] = r[HD + t]; w2[j] = r[2 * HD + t];
            }
            #pragma unroll
            for (int a = 0; a < AG; ++a) {
                float4 v0 = *(const float4*)&xs[a][kc];
                float4 v1 = *(const float4*)&xs[a][kc + 4];
                gi0[a] = dot8w(v0, v1, w0, gi0[a]);
                gi1[a] = dot8w(v0, v1, w1, gi1[a]);
                gi2[a] = dot8w(v0, v1, w2, gi2[a]);
            }
        }
        for (int kc = 0; kc < HD; kc += 8) {       // gh = h @ W_h
            float w0[8], w1[8], w2[8];
            #pragma unroll
            for (int j = 0; j < 8; ++j) {
                const float* r = W_h + (size_t)(kc + j) * (3 * HD);
                w0[j] = r[t]; w1[j] = r[HD + t]; w2[j] = r[2 * HD + t];
            }
            #pragma unroll
            for (int a = 0; a < AG; ++a) {
                float4 v0 = *(const float4*)&hrs[a][kc];
                float4 v1 = *(const float4*)&hrs[a][kc + 4];
                gh0[a] = dot8w(v0, v1, w0, gh0[a]);
                gh1[a] = dot8w(v0, v1, w1, gh1[a]);
                gh2[a] = dot8w(v0, v1, w2, gh2[a]);
            }
        }
        #pragma unroll
        for (int a = 0; a < AG; ++a) {
            float rg = 1.f / (1.f + __expf(-(gi0[a] + gh0[a])));
            float zg = 1.f / (1.f + __expf(-(gi1[a] + gh1[a])));
            float ng = tanhf(gi2[a] + rg * gh2[a]);
            float hn = (1.f - zg) * ng + zg * hrs[a][t];
            hnreg[a] = hn;
            hnew[a][t] = hn;
            out[QN + (size_t)(a0 + a) * HD + t] = hn;   // second output
        }
    }
    __syncthreads();

    // ---------------- stage 4+5: e1 MLP + e2 heads, per agent ----------------
    // h_new contribution (identical across an agent's 16 edges) via K-chunked GEMV
    float hacc[AG];
    {
        const float be1 = b_e1[t];
        #pragma unroll
        for (int a = 0; a < AG; ++a) hacc[a] = be1;
    }
    for (int kc = 0; kc < HD; kc += 8) {
        float w[8];
        #pragma unroll
        for (int j = 0; j < 8; ++j) w[j] = W_e1[(size_t)(FNBR + kc + j) * HD + t];
        #pragma unroll
        for (int a = 0; a < AG; ++a)
            hacc[a] = dot8w(*(const float4*)&hnew[a][kc], *(const float4*)&hnew[a][kc + 4], w, hacc[a]);
    }
    // fn/ef-part weights in 40 regs, reused across all AG*16 edges
    float we[FNBR + FHOP];
    #pragma unroll
    for (int k = 0; k < FNBR; ++k) we[k] = W_e1[(size_t)k * HD + t];
    #pragma unroll
    for (int k = 0; k < FHOP; ++k) we[FNBR + k] = W_e1[(size_t)(FNBR + HD + k) * HD + t];
    const float wa0 = W_a[t], wa1 = W_a[HD + t];
    const float be2v = b_e2[t & 3];
    const float ba = b_a[0];

    for (int a = 0; a < AG; ++a) {
        float agg2 = 0.f;
        #pragma unroll 2
        for (int e = 0; e < MAXN; ++e) {
            const int ee = a * MAXN + e;
            const float4* fnv = (const float4*)&fn[ee][0];
            const float4* efv = (const float4*)&ef[ee][0];
            float p0 = hacc[a], p1 = 0.f;
            p0 = dot8w(fnv[0], fnv[1], &we[0],  p0);
            p1 = dot8w(fnv[2], fnv[3], &we[8],  p1);
            p0 = dot8w(fnv[4], fnv[5], &we[16], p0);
            p1 = dot8w(fnv[6], fnv[7], &we[24], p1);
            p0 = dot4w(efv[0], &we[32], p0);
            p1 = dot4w(efv[1], &we[36], p1);
            float z = fmaxf(p0 + p1, 0.f);
            ze[e][t] = z;
            agg2 += z;
        }
        red[t] = fmaf(agg2, wa0, hnreg[a] * wa1);
        __syncthreads();

        // e2: thread = (edge e, slot s); s = p + 4*khalf; pairs combine via shfl
        {
            const int e = t >> 3, s = t & 7, p = s & 3, kh = (s >> 2) * 64;
            float acc4 = 0.f;
            #pragma unroll
            for (int k = 0; k < 64; k += 4) {
                float4 zv = *(const float4*)&ze[e][kh + k];
                acc4 = fmaf(zv.x, w2s[(kh + k + 0) * NPOW + p], acc4);
                acc4 = fmaf(zv.y, w2s[(kh + k + 1) * NPOW + p], acc4);
                acc4 = fmaf(zv.z, w2s[(kh + k + 2) * NPOW + p], acc4);
                acc4 = fmaf(zv.w, w2s[(kh + k + 3) * NPOW + p], acc4);
            }
            acc4 += __shfl_down(acc4, 4);
            if (s < 4) out[(size_t)(a0 + a) * QCOLS + (e * NPOW + p)] = acc4 + be2v;
        }
        // agent scalar head
        if (t < 64) {
            float v = red[t] + red[t + 64];
            #pragma unroll
            for (int off = 32; off > 0; off >>= 1) v += __shfl_down(v, off);
            if (t == 0) out[(size_t)(a0 + a) * QCOLS + 64] = v + ba;
        }
        __syncthreads();   // ze/red reused by next agent
    }
}

extern "C" void kernel_launch(void* const* d_in, const int* in_sizes, int n_in,
                              void* d_out, int out_size, void* d_ws, size_t ws_size,
                              hipStream_t stream) {
    const float* feat_nbr   = (const float*)d_in[0];
    const float* feat_agent = (const float*)d_in[1];
    const float* edge_feat  = (const float*)d_in[2];
    const float* h_in       = (const float*)d_in[3];
    const float* W_msg = (const float*)d_in[4];
    const float* b_msg = (const float*)d_in[5];
    const float* W_upd = (const float*)d_in[6];
    const float* b_upd = (const float*)d_in[7];
    const float* W_x   = (const float*)d_in[8];
    const float* W_h   = (const float*)d_in[9];
    const float* b_ih  = (const float*)d_in[10];
    const float* b_hh  = (const float*)d_in[11];
    const float* W_e1  = (const float*)d_in[12];
    const float* b_e1  = (const float*)d_in[13];
    const float* W_e2  = (const float*)d_in[14];
    const float* b_e2  = (const float*)d_in[15];
    const float* W_a   = (const float*)d_in[16];
    const float* b_a   = (const float*)d_in[17];
    const int* src_idx = (const int*)d_in[18];
    // d_in[19] = dst_idx unused: edges are grouped by dst with fixed degree 16.
    float* out = (float*)d_out;

    fused_gnn<<<NAGENT / AG, 128, 0, stream>>>(
        feat_nbr, feat_agent, edge_feat, h_in,
        W_msg, b_msg, W_upd, b_upd,
        W_x, W_h, b_ih, b_hh,
        W_e1, b_e1, W_e2, b_e2, W_a, b_a,
        src_idx, out);
}

// Round 4
// 399.896 us; speedup vs baseline: 2.0135x; 1.5968x over previous
//
#include <hip/hip_runtime.h>

typedef _Float16 half_t;
typedef half_t half8 __attribute__((ext_vector_type(8)));
typedef half_t half4 __attribute__((ext_vector_type(4)));
typedef float f32x4 __attribute__((ext_vector_type(4)));

#define NAGENT 32768
#define MAXN   16
#define HD     128
#define QCOLS  65
#define QN     (NAGENT * QCOLS)
#define AGB    8                 // agents per block
#define EPB    (AGB * MAXN)      // 128 edges per block

// ws layout (half_t element offsets) — f16 transposed weights WT[n][k]
#define O_WMT   0                // [128][64]  W_msg  (k: fn 0..31, ef 32..39, 0-pad)
#define O_WE1E  8192             // [128][64]  W_e1 edge part (fn rows 0..31, ef rows 160..167)
#define O_WE1H  16384            // [128][128] W_e1 h part (rows 32..159)
#define O_WUPD  32768            // [128][160] W_upd
#define O_WX    53248            // [384][128] W_x
#define O_WH    102400           // [384][128] W_h
#define W_TOTAL 151552

#define MFMA(a, b, c) __builtin_amdgcn_mfma_f32_16x16x32_f16((a), (b), (c), 0, 0, 0)

__global__ void prep_weights(const float* __restrict__ W_msg, const float* __restrict__ W_upd,
                             const float* __restrict__ W_x, const float* __restrict__ W_h,
                             const float* __restrict__ W_e1, half_t* __restrict__ ws) {
    int i = blockIdx.x * 256 + threadIdx.x;
    if (i >= W_TOTAL) return;
    float v;
    if (i < O_WE1E) {                       // wmT[n][k]
        int j = i - O_WMT; int n = j >> 6, k = j & 63;
        v = (k < 40) ? W_msg[k * HD + n] : 0.f;
    } else if (i < O_WE1H) {                // we1eT[n][k]: e1 concat order is [fn, h, ef]
        int j = i - O_WE1E; int n = j >> 6, k = j & 63;
        v = (k < 32) ? W_e1[k * HD + n] : (k < 40 ? W_e1[(160 + k - 32) * HD + n] : 0.f);
    } else if (i < O_WUPD) {                // we1hT[n][k] = W_e1 rows 32..159
        int j = i - O_WE1H; int n = j >> 7, k = j & 127;
        v = W_e1[(32 + k) * HD + n];
    } else if (i < O_WX) {                  // wupdT[n][k], K=160 = [agg|fa]
        int j = i - O_WUPD; int n = j / 160, k = j - n * 160;
        v = W_upd[k * HD + n];
    } else if (i < O_WH) {                  // wxT[n][k], n in [0,384)
        int j = i - O_WX; int n = j >> 7, k = j & 127;
        v = W_x[k * 384 + n];
    } else {
        int j = i - O_WH; int n = j >> 7, k = j & 127;
        v = W_h[k * 384 + n];
    }
    ws[i] = (half_t)v;
}

__device__ __forceinline__ half8 ldB(const half_t* __restrict__ WT, int kstride, int n0, int k0, int l) {
    return *(const half8*)(WT + (size_t)(n0 + (l & 15)) * kstride + k0 + ((l >> 4) * 8));
}
__device__ __forceinline__ float sigm(float x) { return 1.f / (1.f + __expf(-x)); }
__device__ __forceinline__ float tanh_fast(float x) { return 1.f - 2.f / (__expf(2.f * x) + 1.f); }

__global__ __launch_bounds__(128) void fused_gnn(
    const float* __restrict__ feat_nbr, const float* __restrict__ feat_agent,
    const float* __restrict__ edge_feat, const float* __restrict__ h_in,
    const float* __restrict__ b_msg, const float* __restrict__ b_upd,
    const float* __restrict__ b_ih, const float* __restrict__ b_hh,
    const float* __restrict__ b_e1, const float* __restrict__ W_e2,
    const float* __restrict__ b_e2, const float* __restrict__ W_a,
    const float* __restrict__ b_a, const int* __restrict__ src_idx,
    const half_t* __restrict__ ws, float* __restrict__ out)
{
    const int t = threadIdx.x;
    const int w = t >> 6;            // wave id (2 waves)
    const int l = t & 63;            // lane
    const int l16 = l & 15, q = l >> 4;
    const int a0 = blockIdx.x * AGB;
    const int be = blockIdx.x * EPB;

    const half_t* wmT   = ws + O_WMT;
    const half_t* we1eT = ws + O_WE1E;
    const half_t* we1hT = ws + O_WE1H;
    const half_t* wupdT = ws + O_WUPD;
    const half_t* wxT   = ws + O_WX;
    const half_t* whT   = ws + O_WH;

    // strides chosen so A-frag ds_read_b128 lands at 2-way bank aliasing (free, m136)
    __shared__ half_t A_lds[EPB][56];    // [fn(0..31) | ef(32..39) | pad] per edge
    __shared__ half_t A2[16][168];       // [agg(0..127) | fa(128..159) | pad]; rows 8..15 zero
    __shared__ half_t x_lds[16][136];    // rows 8..15 zero
    __shared__ half_t h_lds[16][136];    // rows 8..15 zero
    __shared__ half_t hn_lds[16][136];   // rows 8..15 zero
    __shared__ half_t che[AGB][136];     // h_new@We1h + b_e1
    __shared__ float  agg2s[AGB][132];
    __shared__ int    srcs[EPB];

    const half8 hz = {0, 0, 0, 0, 0, 0, 0, 0};

    // ---------------- S0: stage inputs (f32 -> f16 in-kernel) ----------------
    srcs[t] = src_idx[be + t];
    {   // zero M-rows 8..15 of the M=8 A-operand arrays (read by MFMA frags)
        int* z0 = (int*)&A2[8][0];     for (int i = t; i < 8 * 84; i += 128) z0[i] = 0;
        int* z1 = (int*)&x_lds[8][0];  for (int i = t; i < 8 * 68; i += 128) z1[i] = 0;
        int* z2 = (int*)&h_lds[8][0];  for (int i = t; i < 8 * 68; i += 128) z2[i] = 0;
        int* z3 = (int*)&hn_lds[8][0]; for (int i = t; i < 8 * 68; i += 128) z3[i] = 0;
    }
    __syncthreads();
    #pragma unroll
    for (int i = 0; i < 8; ++i) {        // fn gather: 128 rows x 8 float4 chunks
        int g = t + 128 * i; int e = g >> 3, p = g & 7;
        float4 v = ((const float4*)(feat_nbr + (size_t)srcs[e] * 32))[p];
        *(half4*)&A_lds[e][p * 4] = (half4){(half_t)v.x, (half_t)v.y, (half_t)v.z, (half_t)v.w};
    }
    #pragma unroll
    for (int i = 0; i < 2; ++i) {        // ef: contiguous 256 float4
        int g = t + 128 * i; int e = g >> 1, p = g & 1;
        float4 v = ((const float4*)(edge_feat + (size_t)be * 8))[g];
        *(half4*)&A_lds[e][32 + p * 4] = (half4){(half_t)v.x, (half_t)v.y, (half_t)v.z, (half_t)v.w};
    }
    #pragma unroll
    for (int i = 0; i < 2; ++i) {        // h: 8 rows x 32 float4
        int g = t + 128 * i; int r = g >> 5, c = g & 31;
        float4 v = ((const float4*)(h_in + (size_t)a0 * HD))[g];
        *(half4*)&h_lds[r][c * 4] = (half4){(half_t)v.x, (half_t)v.y, (half_t)v.z, (half_t)v.w};
    }
    if (t < 64) {                        // fa -> A2 cols 128..159
        int r = t >> 3, p = t & 7;
        float4 v = ((const float4*)(feat_agent + (size_t)a0 * 32))[t];
        *(half4*)&A2[r][128 + p * 4] = (half4){(half_t)v.x, (half_t)v.y, (half_t)v.z, (half_t)v.w};
    }
    __syncthreads();

    // ---------------- S1: m = relu([fn|ef]@Wmsg + b); agg -> A2 cols 0..127 --
    // M-tile == one agent's 16 edges; rowsum of relu'd C-tile = segment_sum.
    #pragma unroll
    for (int mt = 0; mt < 4; ++mt) {
        const int al = w * 4 + mt;       // local agent
        const int arow = al * 16 + l16;
        half8 af0 = *(const half8*)&A_lds[arow][q * 8];
        half8 af1 = (q == 0) ? *(const half8*)&A_lds[arow][32] : hz;  // K-step1: only k=32..39 real
        #pragma unroll
        for (int nc = 0; nc < 4; ++nc) {
            const int n0 = nc * 32;
            f32x4 c0 = {0.f, 0.f, 0.f, 0.f}, c1 = {0.f, 0.f, 0.f, 0.f};
            c0 = MFMA(af0, ldB(wmT, 64, n0, 0, l), c0);
            c0 = MFMA(af1, ldB(wmT, 64, n0, 32, l), c0);
            c1 = MFMA(af0, ldB(wmT, 64, n0 + 16, 0, l), c1);
            c1 = MFMA(af1, ldB(wmT, 64, n0 + 16, 32, l), c1);
            float bm0 = b_msg[n0 + l16], bm1 = b_msg[n0 + 16 + l16];
            float s0 = 0.f, s1 = 0.f;
            #pragma unroll
            for (int r = 0; r < 4; ++r) {
                s0 += fmaxf(c0[r] + bm0, 0.f);
                s1 += fmaxf(c1[r] + bm1, 0.f);
            }
            s0 += __shfl_xor(s0, 16); s0 += __shfl_xor(s0, 32);
            s1 += __shfl_xor(s1, 16); s1 += __shfl_xor(s1, 32);
            if (l < 16) {
                A2[al][n0 + l] = (half_t)s0;
                A2[al][n0 + 16 + l] = (half_t)s1;
            }
        }
    }
    __syncthreads();

    // ---------------- S2: x = relu([agg|fa]@Wupd + b) ------------------------
    {
        half8 af[5];
        #pragma unroll
        for (int k = 0; k < 5; ++k) af[k] = *(const half8*)&A2[l16][k * 32 + q * 8];
        #pragma unroll
        for (int nt = 0; nt < 4; ++nt) {
            const int n0 = (w * 4 + nt) * 16;
            f32x4 c = {0.f, 0.f, 0.f, 0.f};
            #pragma unroll
            for (int k = 0; k < 5; ++k) c = MFMA(af[k], ldB(wupdT, 160, n0, k * 32, l), c);
            float bu = b_upd[n0 + l16];
            if (q < 2) {                 // C rows 0..7 valid (M=8)
                #pragma unroll
                for (int r = 0; r < 4; ++r)
                    x_lds[q * 4 + r][n0 + l16] = (half_t)fmaxf(c[r] + bu, 0.f);
            }
        }
    }
    __syncthreads();

    // ---------------- S3: GRU (gi = x@Wx, gh = h@Wh, elementwise in-frag) ----
    {
        half8 ax[4], ah[4];
        #pragma unroll
        for (int k = 0; k < 4; ++k) {
            ax[k] = *(const half8*)&x_lds[l16][k * 32 + q * 8];
            ah[k] = *(const half8*)&h_lds[l16][k * 32 + q * 8];
        }
        f32x4 gi[3][4], gh[3][4];        // [gate r/z/n][col-subtile], wave owns cols 64w..64w+63
        #pragma unroll
        for (int g = 0; g < 3; ++g) {
            #pragma unroll
            for (int s = 0; s < 4; ++s) {
                const int n0 = g * 128 + w * 64 + s * 16;
                f32x4 ci = {0.f, 0.f, 0.f, 0.f}, ch = {0.f, 0.f, 0.f, 0.f};
                #pragma unroll
                for (int k = 0; k < 4; ++k) {
                    ci = MFMA(ax[k], ldB(wxT, 128, n0, k * 32, l), ci);
                    ch = MFMA(ah[k], ldB(whT, 128, n0, k * 32, l), ch);
                }
                gi[g][s] = ci; gh[g][s] = ch;
            }
        }
        #pragma unroll
        for (int s = 0; s < 4; ++s) {
            const int col = w * 64 + s * 16 + l16;
            float bi0 = b_ih[col], bi1 = b_ih[HD + col], bi2 = b_ih[2 * HD + col];
            float bh0 = b_hh[col], bh1 = b_hh[HD + col], bh2 = b_hh[2 * HD + col];
            #pragma unroll
            for (int r = 0; r < 4; ++r) {
                const int row = q * 4 + r;
                float rg = sigm(gi[0][s][r] + bi0 + gh[0][s][r] + bh0);
                float zg = sigm(gi[1][s][r] + bi1 + gh[1][s][r] + bh1);
                float ng = tanh_fast(gi[2][s][r] + bi2 + rg * (gh[2][s][r] + bh2));
                float hv = (1.f - zg) * ng + zg * (float)h_lds[row][col];
                if (row < 8) {
                    out[QN + (size_t)(a0 + row) * HD + col] = hv;   // output 1: h_new
                    hn_lds[row][col] = (half_t)hv;
                }
            }
        }
    }
    __syncthreads();

    // ---------------- S4h: che = h_new @ We1h + b_e1 (per-agent, hoisted) ----
    {
        half8 an[4];
        #pragma unroll
        for (int k = 0; k < 4; ++k) an[k] = *(const half8*)&hn_lds[l16][k * 32 + q * 8];
        #pragma unroll
        for (int nt = 0; nt < 4; ++nt) {
            const int n0 = (w * 4 + nt) * 16;
            f32x4 c = {0.f, 0.f, 0.f, 0.f};
            #pragma unroll
            for (int k = 0; k < 4; ++k) c = MFMA(an[k], ldB(we1hT, 128, n0, k * 32, l), c);
            float bv = b_e1[n0 + l16];
            if (q < 2) {
                #pragma unroll
                for (int r = 0; r < 4; ++r) che[q * 4 + r][n0 + l16] = (half_t)(c[r] + bv);
            }
        }
    }
    __syncthreads();

    // ------- S4e+S5: ze = relu([fn|ef]@We1e + che); agg2; nbr q-values -------
    #pragma unroll
    for (int mt = 0; mt < 4; ++mt) {
        const int al = w * 4 + mt;
        const int arow = al * 16 + l16;
        half8 af0 = *(const half8*)&A_lds[arow][q * 8];
        half8 af1 = (q == 0) ? *(const half8*)&A_lds[arow][32] : hz;
        float qa[4][4];                  // [row r][pow p] partials over this lane's cols
        #pragma unroll
        for (int r = 0; r < 4; ++r) {
            #pragma unroll
            for (int p = 0; p < 4; ++p) qa[r][p] = 0.f;
        }
        #pragma unroll
        for (int nc = 0; nc < 4; ++nc) {
            const int n0 = nc * 32;
            f32x4 c0 = {0.f, 0.f, 0.f, 0.f}, c1 = {0.f, 0.f, 0.f, 0.f};
            c0 = MFMA(af0, ldB(we1eT, 64, n0, 0, l), c0);
            c0 = MFMA(af1, ldB(we1eT, 64, n0, 32, l), c0);
            c1 = MFMA(af0, ldB(we1eT, 64, n0 + 16, 0, l), c1);
            c1 = MFMA(af1, ldB(we1eT, 64, n0 + 16, 32, l), c1);
            const int col0 = n0 + l16, col1 = n0 + 16 + l16;
            float ch0 = (float)che[al][col0], ch1 = (float)che[al][col1];
            float4 w20 = *(const float4*)(W_e2 + col0 * 4);
            float4 w21 = *(const float4*)(W_e2 + col1 * 4);
            float s0 = 0.f, s1 = 0.f;
            #pragma unroll
            for (int r = 0; r < 4; ++r) {
                float z0 = fmaxf(c0[r] + ch0, 0.f);
                float z1 = fmaxf(c1[r] + ch1, 0.f);
                s0 += z0; s1 += z1;
                qa[r][0] = fmaf(z0, w20.x, fmaf(z1, w21.x, qa[r][0]));
                qa[r][1] = fmaf(z0, w20.y, fmaf(z1, w21.y, qa[r][1]));
                qa[r][2] = fmaf(z0, w20.z, fmaf(z1, w21.z, qa[r][2]));
                qa[r][3] = fmaf(z0, w20.w, fmaf(z1, w21.w, qa[r][3]));
            }
            s0 += __shfl_xor(s0, 16); s0 += __shfl_xor(s0, 32);
            s1 += __shfl_xor(s1, 16); s1 += __shfl_xor(s1, 32);
            if (l < 16) {
                agg2s[al][col0] = s0;
                agg2s[al][col1] = s1;
            }
        }
        #pragma unroll
        for (int m = 1; m <= 8; m <<= 1) {
            #pragma unroll
            for (int r = 0; r < 4; ++r) {
                #pragma unroll
                for (int p = 0; p < 4; ++p) qa[r][p] += __shfl_xor(qa[r][p], m);
            }
        }
        if (l16 < 4) {
            const int p = l16;
            const float bz = b_e2[p];
            #pragma unroll
            for (int r = 0; r < 4; ++r) {
                const int edge = q * 4 + r;   // out col = edge*4 + p (matches reshape)
                out[(size_t)(a0 + al) * QCOLS + edge * 4 + p] = qa[r][p] + bz;
            }
        }
    }
    __syncthreads();

    // ---------------- agent scalar head: [agg2|h_new]@W_a + b_a --------------
    {
        const int a = t >> 4, j = t & 15;
        float s = 0.f;
        #pragma unroll
        for (int i = 0; i < 8; ++i) {
            const int c = j + 16 * i;
            s = fmaf(agg2s[a][c], W_a[c], s);
            s = fmaf((float)hn_lds[a][c], W_a[HD + c], s);
        }
        #pragma unroll
        for (int m = 1; m <= 8; m <<= 1) s += __shfl_xor(s, m);
        if (j == 0) out[(size_t)(a0 + a) * QCOLS + 64] = s + b_a[0];
    }
}

extern "C" void kernel_launch(void* const* d_in, const int* in_sizes, int n_in,
                              void* d_out, int out_size, void* d_ws, size_t ws_size,
                              hipStream_t stream) {
    const float* feat_nbr   = (const float*)d_in[0];
    const float* feat_agent = (const float*)d_in[1];
    const float* edge_feat  = (const float*)d_in[2];
    const float* h_in       = (const float*)d_in[3];
    const float* W_msg = (const float*)d_in[4];
    const float* b_msg = (const float*)d_in[5];
    const float* W_upd = (const float*)d_in[6];
    const float* b_upd = (const float*)d_in[7];
    const float* W_x   = (const float*)d_in[8];
    const float* W_h   = (const float*)d_in[9];
    const float* b_ih  = (const float*)d_in[10];
    const float* b_hh  = (const float*)d_in[11];
    const float* W_e1  = (const float*)d_in[12];
    const float* b_e1  = (const float*)d_in[13];
    const float* W_e2  = (const float*)d_in[14];
    const float* b_e2  = (const float*)d_in[15];
    const float* W_a   = (const float*)d_in[16];
    const float* b_a   = (const float*)d_in[17];
    const int* src_idx = (const int*)d_in[18];
    // d_in[19] = dst_idx unused: edges grouped by dst, fixed degree 16.
    half_t* ws = (half_t*)d_ws;
    float* out = (float*)d_out;

    prep_weights<<<(W_TOTAL + 255) / 256, 256, 0, stream>>>(W_msg, W_upd, W_x, W_h, W_e1, ws);
    fused_gnn<<<NAGENT / AGB, 128, 0, stream>>>(
        feat_nbr, feat_agent, edge_feat, h_in,
        b_msg, b_upd, b_ih, b_hh, b_e1,
        W_e2, b_e2, W_a, b_a, src_idx, ws, out);
}

// Round 5
// 339.281 us; speedup vs baseline: 2.3733x; 1.1787x over previous
//
#include <hip/hip_runtime.h>

typedef _Float16 half_t;
typedef half_t half8 __attribute__((ext_vector_type(8)));
typedef half_t half4 __attribute__((ext_vector_type(4)));
typedef float f32x4 __attribute__((ext_vector_type(4)));

#define NAGENT 32768
#define MAXN   16
#define HD     128
#define QCOLS  65
#define QN     (NAGENT * QCOLS)
#define AGB    16                // agents per block
#define EPB    (AGB * MAXN)     // 256 edges per block

// ws layout (half_t element offsets) — f16 transposed weights WT[n][k]
#define O_WMT   0                // [128][64]  W_msg  (k: fn 0..31, ef 32..39, 0-pad)
#define O_WE1E  8192             // [128][64]  W_e1 edge part (fn rows 0..31, ef rows 160..167)
#define O_WE1H  16384            // [128][128] W_e1 h part (rows 32..159)
#define O_WUPD  32768            // [128][160] W_upd
#define O_WX    53248            // [384][128] W_x
#define O_WH    102400           // [384][128] W_h
#define W_TOTAL 151552

#define MFMA(a, b, c) __builtin_amdgcn_mfma_f32_16x16x32_f16((a), (b), (c), 0, 0, 0)

// Read-coalesced transpose (R4's version read source at stride 512-1536B; the
// scattered side is now the WRITE, which doesn't stall the wave).
__global__ void prep_weights(const float* __restrict__ W_msg, const float* __restrict__ W_upd,
                             const float* __restrict__ W_x, const float* __restrict__ W_h,
                             const float* __restrict__ W_e1, half_t* __restrict__ ws) {
    int i = blockIdx.x * 256 + threadIdx.x;
    if (i >= W_TOTAL) return;
    float v; int dst;
    if (i < 8192) {                          // wmT[n][k], Kp=64
        int k = i >> 7, n = i & 127;
        v = (k < 40) ? W_msg[k * HD + n] : 0.f;
        dst = O_WMT + n * 64 + k;
    } else if (i < 16384) {                  // we1eT[n][k]: e1 concat order [fn, h, ef]
        int j = i - 8192; int k = j >> 7, n = j & 127;
        v = (k < 32) ? W_e1[k * HD + n] : (k < 40 ? W_e1[(160 + k - 32) * HD + n] : 0.f);
        dst = O_WE1E + n * 64 + k;
    } else if (i < 32768) {                  // we1hT[n][k] = W_e1 rows 32..159
        int j = i - 16384; int k = j >> 7, n = j & 127;
        v = W_e1[(32 + k) * HD + n];
        dst = O_WE1H + n * 128 + k;
    } else if (i < 53248) {                  // wupdT[n][k], K=160 = [agg|fa]
        int j = i - 32768; int k = j >> 7, n = j & 127;
        v = W_upd[k * HD + n];
        dst = O_WUPD + n * 160 + k;
    } else if (i < 102400) {                 // wxT[n][k], n in [0,384)
        int j = i - 53248; int k = j / 384, n = j - k * 384;
        v = W_x[k * 384 + n];
        dst = O_WX + n * 128 + k;
    } else {
        int j = i - 102400; int k = j / 384, n = j - k * 384;
        v = W_h[k * 384 + n];
        dst = O_WH + n * 128 + k;
    }
    ws[dst] = (half_t)v;
}

__device__ __forceinline__ half8 ldB(const half_t* __restrict__ WT, int kstride, int n0, int k0, int l) {
    return *(const half8*)(WT + (size_t)(n0 + (l & 15)) * kstride + k0 + ((l >> 4) * 8));
}
__device__ __forceinline__ half4 cvt4(float4 v) {
    return (half4){(half_t)v.x, (half_t)v.y, (half_t)v.z, (half_t)v.w};
}
__device__ __forceinline__ half8 cvt8(float4 a, float4 b) {
    return (half8){(half_t)a.x, (half_t)a.y, (half_t)a.z, (half_t)a.w,
                   (half_t)b.x, (half_t)b.y, (half_t)b.z, (half_t)b.w};
}
__device__ __forceinline__ float sigm(float x) { return 1.f / (1.f + __expf(-x)); }
__device__ __forceinline__ float tanh_fast(float x) { return 1.f - 2.f / (__expf(2.f * x) + 1.f); }

__global__ __launch_bounds__(256, 4) void fused_gnn(
    const float* __restrict__ feat_nbr, const float* __restrict__ feat_agent,
    const float* __restrict__ edge_feat, const float* __restrict__ h_in,
    const float* __restrict__ b_msg, const float* __restrict__ b_upd,
    const float* __restrict__ b_ih, const float* __restrict__ b_hh,
    const float* __restrict__ b_e1, const float* __restrict__ W_e2,
    const float* __restrict__ b_e2, const float* __restrict__ W_a,
    const float* __restrict__ b_a, const int* __restrict__ src_idx,
    const half_t* __restrict__ ws, float* __restrict__ out)
{
    const int t = threadIdx.x;
    const int w = t >> 6;            // wave id (4 waves)
    const int l = t & 63;
    const int l16 = l & 15, q = l >> 4;
    const int a0 = blockIdx.x * AGB;
    const int be = blockIdx.x * EPB;

    const half_t* wmT   = ws + O_WMT;
    const half_t* we1eT = ws + O_WE1E;
    const half_t* we1hT = ws + O_WE1H;
    const half_t* wupdT = ws + O_WUPD;
    const half_t* wxT   = ws + O_WX;
    const half_t* whT   = ws + O_WH;

    // ~24 KB LDS -> 4 blocks/CU x 4 waves = 16 waves/CU (2x R4)
    __shared__ half_t A2[AGB][168];      // [agg(0..127) | fa(128..159) | pad]
    __shared__ half_t x_lds[AGB][136];
    __shared__ half_t h_lds[AGB][136];
    __shared__ half_t hn_lds[AGB][136];
    __shared__ half_t che[AGB][136];     // h_new@We1h + b_e1
    __shared__ int    srcs[EPB];

    const half8 hz = {0, 0, 0, 0, 0, 0, 0, 0};

    // ---------------- S0: stage small inputs --------------------------------
    srcs[t] = src_idx[be + t];
    #pragma unroll
    for (int i = 0; i < 2; ++i) {        // h: 16 rows x 32 float4
        int g = t + 256 * i; int r = g >> 5, c = g & 31;
        float4 v = ((const float4*)(h_in + (size_t)(a0 + r) * HD))[c];
        *(half4*)&h_lds[r][c * 4] = cvt4(v);
    }
    if (t < 128) {                       // fa -> A2 cols 128..159
        int r = t >> 3, p = t & 7;
        float4 v = ((const float4*)(feat_agent + (size_t)(a0 + r) * 32))[p];
        *(half4*)&A2[r][128 + p * 4] = cvt4(v);
    }
    __syncthreads();

    // ---------------- S1: m = relu([fn|ef]@Wmsg + b); rowsum -> agg ---------
    // A-fragments loaded straight from global (lane = 32B of one fn row).
    #pragma unroll
    for (int mt = 0; mt < 4; ++mt) {
        const int al = w * 4 + mt;       // local agent
        const int arow = al * 16 + l16;
        const float* fr = feat_nbr + (size_t)srcs[arow] * 32 + q * 8;
        half8 af0 = cvt8(*(const float4*)fr, *(const float4*)(fr + 4));
        half8 af1 = hz;
        if (q == 0) {
            const float* er = edge_feat + (size_t)(be + arow) * 8;
            af1 = cvt8(*(const float4*)er, *(const float4*)(er + 4));
        }
        #pragma unroll
        for (int nc = 0; nc < 4; ++nc) {
            const int n0 = nc * 32;
            f32x4 c0 = {0.f, 0.f, 0.f, 0.f}, c1 = {0.f, 0.f, 0.f, 0.f};
            c0 = MFMA(af0, ldB(wmT, 64, n0, 0, l), c0);
            c0 = MFMA(af1, ldB(wmT, 64, n0, 32, l), c0);
            c1 = MFMA(af0, ldB(wmT, 64, n0 + 16, 0, l), c1);
            c1 = MFMA(af1, ldB(wmT, 64, n0 + 16, 32, l), c1);
            float bm0 = b_msg[n0 + l16], bm1 = b_msg[n0 + 16 + l16];
            float s0 = 0.f, s1 = 0.f;
            #pragma unroll
            for (int r = 0; r < 4; ++r) {
                s0 += fmaxf(c0[r] + bm0, 0.f);
                s1 += fmaxf(c1[r] + bm1, 0.f);
            }
            s0 += __shfl_xor(s0, 16); s0 += __shfl_xor(s0, 32);
            s1 += __shfl_xor(s1, 16); s1 += __shfl_xor(s1, 32);
            if (l < 16) {
                A2[al][n0 + l] = (half_t)s0;
                A2[al][n0 + 16 + l] = (half_t)s1;
            }
        }
    }
    __syncthreads();

    // ---------------- S2: x = relu([agg|fa]@Wupd + b), M=16 full ------------
    {
        half8 af[5];
        #pragma unroll
        for (int k = 0; k < 5; ++k) af[k] = *(const half8*)&A2[l16][k * 32 + q * 8];
        #pragma unroll
        for (int s = 0; s < 2; ++s) {
            const int n0 = (w * 2 + s) * 16;
            f32x4 c = {0.f, 0.f, 0.f, 0.f};
            #pragma unroll
            for (int k = 0; k < 5; ++k) c = MFMA(af[k], ldB(wupdT, 160, n0, k * 32, l), c);
            float bu = b_upd[n0 + l16];
            #pragma unroll
            for (int r = 0; r < 4; ++r)
                x_lds[q * 4 + r][n0 + l16] = (half_t)fmaxf(c[r] + bu, 0.f);
        }
    }
    __syncthreads();

    // ---------------- S3: GRU, wave owns h-cols [w*32, w*32+32) -------------
    {
        half8 ax[4], ah[4];
        #pragma unroll
        for (int k = 0; k < 4; ++k) {
            ax[k] = *(const half8*)&x_lds[l16][k * 32 + q * 8];
            ah[k] = *(const half8*)&h_lds[l16][k * 32 + q * 8];
        }
        #pragma unroll
        for (int s = 0; s < 2; ++s) {
            const int colb = w * 32 + s * 16;
            f32x4 gi[3], gh[3];
            #pragma unroll
            for (int g = 0; g < 3; ++g) {
                const int n0 = g * 128 + colb;
                f32x4 ci = {0.f, 0.f, 0.f, 0.f}, ch = {0.f, 0.f, 0.f, 0.f};
                #pragma unroll
                for (int k = 0; k < 4; ++k) {
                    ci = MFMA(ax[k], ldB(wxT, 128, n0, k * 32, l), ci);
                    ch = MFMA(ah[k], ldB(whT, 128, n0, k * 32, l), ch);
                }
                gi[g] = ci; gh[g] = ch;
            }
            const int col = colb + l16;
            float bi0 = b_ih[col], bi1 = b_ih[HD + col], bi2 = b_ih[2 * HD + col];
            float bh0 = b_hh[col], bh1 = b_hh[HD + col], bh2 = b_hh[2 * HD + col];
            #pragma unroll
            for (int r = 0; r < 4; ++r) {
                const int row = q * 4 + r;
                float rg = sigm(gi[0][r] + bi0 + gh[0][r] + bh0);
                float zg = sigm(gi[1][r] + bi1 + gh[1][r] + bh1);
                float ng = tanh_fast(gi[2][r] + bi2 + rg * (gh[2][r] + bh2));
                float hv = (1.f - zg) * ng + zg * (float)h_lds[row][col];
                out[QN + (size_t)(a0 + row) * HD + col] = hv;   // output 1: h_new
                hn_lds[row][col] = (half_t)hv;
            }
        }
    }
    __syncthreads();

    // ---------------- S4h: che = h_new @ We1h + b_e1 ------------------------
    {
        half8 an[4];
        #pragma unroll
        for (int k = 0; k < 4; ++k) an[k] = *(const half8*)&hn_lds[l16][k * 32 + q * 8];
        #pragma unroll
        for (int s = 0; s < 2; ++s) {
            const int n0 = (w * 2 + s) * 16;
            f32x4 c = {0.f, 0.f, 0.f, 0.f};
            #pragma unroll
            for (int k = 0; k < 4; ++k) c = MFMA(an[k], ldB(we1hT, 128, n0, k * 32, l), c);
            float bv = b_e1[n0 + l16];
            #pragma unroll
            for (int r = 0; r < 4; ++r)
                che[q * 4 + r][n0 + l16] = (half_t)(c[r] + bv);
        }
    }
    __syncthreads();

    // ------- S4e+S5: ze = relu([fn|ef]@We1e + che); q-values + heads --------
    {
        const float ba = b_a[0];
        #pragma unroll
        for (int mt = 0; mt < 4; ++mt) {
            const int al = w * 4 + mt;
            const int arow = al * 16 + l16;
            const float* fr = feat_nbr + (size_t)srcs[arow] * 32 + q * 8;
            half8 af0 = cvt8(*(const float4*)fr, *(const float4*)(fr + 4));
            half8 af1 = hz;
            if (q == 0) {
                const float* er = edge_feat + (size_t)(be + arow) * 8;
                af1 = cvt8(*(const float4*)er, *(const float4*)(er + 4));
            }
            float qa[4][4];
            #pragma unroll
            for (int r = 0; r < 4; ++r)
                #pragma unroll
                for (int p = 0; p < 4; ++p) qa[r][p] = 0.f;
            float wa_part = 0.f;         // on-the-fly agg2 . W_a (replaces agg2s LDS)
            #pragma unroll
            for (int nc = 0; nc < 4; ++nc) {
                const int n0 = nc * 32;
                f32x4 c0 = {0.f, 0.f, 0.f, 0.f}, c1 = {0.f, 0.f, 0.f, 0.f};
                c0 = MFMA(af0, ldB(we1eT, 64, n0, 0, l), c0);
                c0 = MFMA(af1, ldB(we1eT, 64, n0, 32, l), c0);
                c1 = MFMA(af0, ldB(we1eT, 64, n0 + 16, 0, l), c1);
                c1 = MFMA(af1, ldB(we1eT, 64, n0 + 16, 32, l), c1);
                const int col0 = n0 + l16, col1 = n0 + 16 + l16;
                float ch0 = (float)che[al][col0], ch1 = (float)che[al][col1];
                float4 w20 = *(const float4*)(W_e2 + col0 * 4);
                float4 w21 = *(const float4*)(W_e2 + col1 * 4);
                float s0 = 0.f, s1 = 0.f;
                #pragma unroll
                for (int r = 0; r < 4; ++r) {
                    float z0 = fmaxf(c0[r] + ch0, 0.f);
                    float z1 = fmaxf(c1[r] + ch1, 0.f);
                    s0 += z0; s1 += z1;
                    qa[r][0] = fmaf(z0, w20.x, fmaf(z1, w21.x, qa[r][0]));
                    qa[r][1] = fmaf(z0, w20.y, fmaf(z1, w21.y, qa[r][1]));
                    qa[r][2] = fmaf(z0, w20.z, fmaf(z1, w21.z, qa[r][2]));
                    qa[r][3] = fmaf(z0, w20.w, fmaf(z1, w21.w, qa[r][3]));
                }
                s0 += __shfl_xor(s0, 16); s0 += __shfl_xor(s0, 32);
                s1 += __shfl_xor(s1, 16); s1 += __shfl_xor(s1, 32);
                wa_part = fmaf(s0, W_a[col0], fmaf(s1, W_a[col1], wa_part));
            }
            #pragma unroll
            for (int m = 1; m <= 8; m <<= 1)
                #pragma unroll
                for (int r = 0; r < 4; ++r)
                    #pragma unroll
                    for (int p = 0; p < 4; ++p) qa[r][p] += __shfl_xor(qa[r][p], m);
            if (l16 < 4) {
                const int p = l16;
                const float bz = b_e2[p];
                #pragma unroll
                for (int r = 0; r < 4; ++r)
                    out[(size_t)(a0 + al) * QCOLS + (q * 4 + r) * 4 + p] = qa[r][p] + bz;
            }
            // agent scalar head: + h_new . W_a[128:256], reduce over l16
            #pragma unroll
            for (int j = 0; j < 8; ++j) {
                const int c = l16 + 16 * j;
                wa_part = fmaf((float)hn_lds[al][c], W_a[HD + c], wa_part);
            }
            #pragma unroll
            for (int m = 1; m <= 8; m <<= 1) wa_part += __shfl_xor(wa_part, m);
            if (l == 0) out[(size_t)(a0 + al) * QCOLS + 64] = wa_part + ba;
        }
    }
}

extern "C" void kernel_launch(void* const* d_in, const int* in_sizes, int n_in,
                              void* d_out, int out_size, void* d_ws, size_t ws_size,
                              hipStream_t stream) {
    const float* feat_nbr   = (const float*)d_in[0];
    const float* feat_agent = (const float*)d_in[1];
    const float* edge_feat  = (const float*)d_in[2];
    const float* h_in       = (const float*)d_in[3];
    const float* W_msg = (const float*)d_in[4];
    const float* b_msg = (const float*)d_in[5];
    const float* W_upd = (const float*)d_in[6];
    const float* b_upd = (const float*)d_in[7];
    const float* W_x   = (const float*)d_in[8];
    const float* W_h   = (const float*)d_in[9];
    const float* b_ih  = (const float*)d_in[10];
    const float* b_hh  = (const float*)d_in[11];
    const float* W_e1  = (const float*)d_in[12];
    const float* b_e1  = (const float*)d_in[13];
    const float* W_e2  = (const float*)d_in[14];
    const float* b_e2  = (const float*)d_in[15];
    const float* W_a   = (const float*)d_in[16];
    const float* b_a   = (const float*)d_in[17];
    const int* src_idx = (const int*)d_in[18];
    // d_in[19] = dst_idx unused: edges grouped by dst, fixed degree 16.
    half_t* ws = (half_t*)d_ws;
    float* out = (float*)d_out;

    prep_weights<<<(W_TOTAL + 255) / 256, 256, 0, stream>>>(W_msg, W_upd, W_x, W_h, W_e1, ws);
    fused_gnn<<<NAGENT / AGB, 256, 0, stream>>>(
        feat_nbr, feat_agent, edge_feat, h_in,
        b_msg, b_upd, b_ih, b_hh, b_e1,
        W_e2, b_e2, W_a, b_a, src_idx, ws, out);
}

// Round 6
// 316.185 us; speedup vs baseline: 2.5466x; 1.0730x over previous
//
#include <hip/hip_runtime.h>

typedef _Float16 half_t;
typedef half_t half8 __attribute__((ext_vector_type(8)));
typedef half_t half4 __attribute__((ext_vector_type(4)));
typedef float f32x4 __attribute__((ext_vector_type(4)));

#define NAGENT 32768
#define MAXN   16
#define HD     128
#define QCOLS  65
#define QN     (NAGENT * QCOLS)
#define AGB    16                // agents per block
#define EPB    (AGB * MAXN)     // 256 edges per block
#define QROWB  260               // bytes per q-row (65 f32)

// ws layout (half_t element offsets) — f16 transposed weights WT[n][k]
#define O_WMT   0                // [128][64]  W_msg  (k: fn 0..31, ef 32..39, 0-pad)
#define O_WE1E  8192             // [128][64]  W_e1 edge part (fn rows 0..31, ef rows 160..167)
#define O_WE1H  16384            // [128][128] W_e1 h part (rows 32..159)
#define O_WUPD  32768            // [128][160] W_upd
#define O_WX    53248            // [384][128] W_x
#define O_WH    102400           // [384][128] W_h
#define W_TOTAL 151552           // + float hn_wa[NAGENT] right after (4B aligned)

#define MFMA(a, b, c) __builtin_amdgcn_mfma_f32_16x16x32_f16((a), (b), (c), 0, 0, 0)

__global__ void prep_weights(const float* __restrict__ W_msg, const float* __restrict__ W_upd,
                             const float* __restrict__ W_x, const float* __restrict__ W_h,
                             const float* __restrict__ W_e1, half_t* __restrict__ ws) {
    int i = blockIdx.x * 256 + threadIdx.x;
    if (i >= W_TOTAL) return;
    float v; int dst;
    if (i < 8192) {                          // wmT[n][k], Kp=64
        int k = i >> 7, n = i & 127;
        v = (k < 40) ? W_msg[k * HD + n] : 0.f;
        dst = O_WMT + n * 64 + k;
    } else if (i < 16384) {                  // we1eT[n][k]: e1 concat order [fn, h, ef]
        int j = i - 8192; int k = j >> 7, n = j & 127;
        v = (k < 32) ? W_e1[k * HD + n] : (k < 40 ? W_e1[(160 + k - 32) * HD + n] : 0.f);
        dst = O_WE1E + n * 64 + k;
    } else if (i < 32768) {                  // we1hT[n][k] = W_e1 rows 32..159
        int j = i - 16384; int k = j >> 7, n = j & 127;
        v = W_e1[(32 + k) * HD + n];
        dst = O_WE1H + n * 128 + k;
    } else if (i < 53248) {                  // wupdT[n][k], K=160 = [agg|fa]
        int j = i - 32768; int k = j >> 7, n = j & 127;
        v = W_upd[k * HD + n];
        dst = O_WUPD + n * 160 + k;
    } else if (i < 102400) {                 // wxT[n][k], n in [0,384)
        int j = i - 53248; int k = j / 384, n = j - k * 384;
        v = W_x[k * 384 + n];
        dst = O_WX + n * 128 + k;
    } else {
        int j = i - 102400; int k = j / 384, n = j - k * 384;
        v = W_h[k * 384 + n];
        dst = O_WH + n * 128 + k;
    }
    ws[dst] = (half_t)v;
}

__device__ __forceinline__ half8 ldB(const half_t* __restrict__ WT, int kstride, int n0, int k0, int l) {
    return *(const half8*)(WT + (size_t)(n0 + (l & 15)) * kstride + k0 + ((l >> 4) * 8));
}
__device__ __forceinline__ half4 cvt4(float4 v) {
    return (half4){(half_t)v.x, (half_t)v.y, (half_t)v.z, (half_t)v.w};
}
__device__ __forceinline__ half8 cvt8(float4 a, float4 b) {
    return (half8){(half_t)a.x, (half_t)a.y, (half_t)a.z, (half_t)a.w,
                   (half_t)b.x, (half_t)b.y, (half_t)b.z, (half_t)b.w};
}
__device__ __forceinline__ float sigm(float x) { return 1.f / (1.f + __expf(-x)); }
__device__ __forceinline__ float tanh_fast(float x) { return 1.f - 2.f / (__expf(2.f * x) + 1.f); }

// ======================= K1: msg GEMM + segment-sum ========================
// agg[a][0:128] (f16) is parked in the q-row of d_out (bytes 0..255 of each
// 260B row); K3 overwrites those bytes with the final q-values.
__global__ __launch_bounds__(256, 2) void k_msg(
    const float* __restrict__ feat_nbr, const float* __restrict__ edge_feat,
    const float* __restrict__ b_msg, const int* __restrict__ src_idx,
    const half_t* __restrict__ ws, float* __restrict__ out)
{
    const int t = threadIdx.x;
    const int w = t >> 6, l = t & 63;
    const int l16 = l & 15, q = l >> 4;
    const int a0 = blockIdx.x * AGB;
    const int be = blockIdx.x * EPB;
    const half_t* wmT = ws + O_WMT;
    const half8 hz = {0, 0, 0, 0, 0, 0, 0, 0};

    __shared__ int srcs[EPB];
    srcs[t] = src_idx[be + t];
    __syncthreads();

    half8 B[4][4];                       // hoisted: same B-frags for all agents
    float bm0[4], bm1[4];
    #pragma unroll
    for (int nc = 0; nc < 4; ++nc) {
        const int n0 = nc * 32;
        B[nc][0] = ldB(wmT, 64, n0, 0, l);
        B[nc][1] = ldB(wmT, 64, n0, 32, l);
        B[nc][2] = ldB(wmT, 64, n0 + 16, 0, l);
        B[nc][3] = ldB(wmT, 64, n0 + 16, 32, l);
        bm0[nc] = b_msg[n0 + l16];
        bm1[nc] = b_msg[n0 + 16 + l16];
    }
    #pragma unroll
    for (int mt = 0; mt < 4; ++mt) {
        const int al = w * 4 + mt;
        const int arow = al * 16 + l16;
        const float* fr = feat_nbr + (size_t)srcs[arow] * 32 + q * 8;
        half8 af0 = cvt8(*(const float4*)fr, *(const float4*)(fr + 4));
        half8 af1 = hz;
        if (q == 0) {
            const float* er = edge_feat + (size_t)(be + arow) * 8;
            af1 = cvt8(*(const float4*)er, *(const float4*)(er + 4));
        }
        half_t* arow_out = (half_t*)((char*)out + (size_t)(a0 + al) * QROWB);
        #pragma unroll
        for (int nc = 0; nc < 4; ++nc) {
            f32x4 c0 = {0.f, 0.f, 0.f, 0.f}, c1 = {0.f, 0.f, 0.f, 0.f};
            c0 = MFMA(af0, B[nc][0], c0);
            c0 = MFMA(af1, B[nc][1], c0);
            c1 = MFMA(af0, B[nc][2], c1);
            c1 = MFMA(af1, B[nc][3], c1);
            float s0 = 0.f, s1 = 0.f;
            #pragma unroll
            for (int r = 0; r < 4; ++r) {
                s0 += fmaxf(c0[r] + bm0[nc], 0.f);
                s1 += fmaxf(c1[r] + bm1[nc], 0.f);
            }
            s0 += __shfl_xor(s0, 16); s0 += __shfl_xor(s0, 32);
            s1 += __shfl_xor(s1, 16); s1 += __shfl_xor(s1, 32);
            if (l < 16) {
                arow_out[nc * 32 + l] = (half_t)s0;
                arow_out[nc * 32 + 16 + l] = (half_t)s1;
            }
        }
    }
}

// ============ K2: node update + GRU + che = h_new@We1h + b_e1 ==============
__global__ __launch_bounds__(256, 2) void k_node(
    const float* __restrict__ feat_agent, const float* __restrict__ h_in,
    const float* __restrict__ b_upd, const float* __restrict__ b_ih,
    const float* __restrict__ b_hh, const float* __restrict__ b_e1,
    const float* __restrict__ W_a, half_t* __restrict__ ws,
    float* __restrict__ out)
{
    const int t = threadIdx.x;
    const int w = t >> 6, l = t & 63;
    const int l16 = l & 15, q = l >> 4;
    const int a0 = blockIdx.x * AGB;
    const half_t* wupdT = ws + O_WUPD;
    const half_t* wxT   = ws + O_WX;
    const half_t* whT   = ws + O_WH;
    const half_t* we1hT = ws + O_WE1H;
    float* hn_wa_g = (float*)(ws + W_TOTAL);

    __shared__ half_t A2[AGB][168];      // [agg(0..127) | fa(128..159) | pad]
    __shared__ half_t h_lds[AGB][136];
    __shared__ half_t x_lds[AGB][136];
    __shared__ half_t hn_lds[AGB][136];
    __shared__ float  hnwa[AGB];

    // ---- S0: stage agg (f16, from out q-rows), fa, h ----
    if (t < AGB) hnwa[t] = 0.f;
    {   // agg: 16 rows x 16 chunks of 16B
        int r = t >> 4, c = t & 15;
        half8 v = *(const half8*)((const char*)out + (size_t)(a0 + r) * QROWB + c * 16);
        *(half8*)&A2[r][c * 8] = v;
    }
    if (t < 128) {
        int r = t >> 3, p = t & 7;
        float4 v = ((const float4*)(feat_agent + (size_t)(a0 + r) * 32))[p];
        *(half4*)&A2[r][128 + p * 4] = cvt4(v);
    }
    #pragma unroll
    for (int i = 0; i < 2; ++i) {
        int g = t + 256 * i; int r = g >> 5, c = g & 31;
        float4 v = ((const float4*)(h_in + (size_t)(a0 + r) * HD))[c];
        *(half4*)&h_lds[r][c * 4] = cvt4(v);
    }
    __syncthreads();

    // ---- S2: x = relu([agg|fa]@Wupd + b) ----
    {
        half8 af[5];
        #pragma unroll
        for (int k = 0; k < 5; ++k) af[k] = *(const half8*)&A2[l16][k * 32 + q * 8];
        #pragma unroll
        for (int s = 0; s < 2; ++s) {
            const int n0 = (w * 2 + s) * 16;
            f32x4 c = {0.f, 0.f, 0.f, 0.f};
            #pragma unroll
            for (int k = 0; k < 5; ++k) c = MFMA(af[k], ldB(wupdT, 160, n0, k * 32, l), c);
            float bu = b_upd[n0 + l16];
            #pragma unroll
            for (int r = 0; r < 4; ++r)
                x_lds[q * 4 + r][n0 + l16] = (half_t)fmaxf(c[r] + bu, 0.f);
        }
    }
    __syncthreads();

    // ---- S3: GRU; fold h_new . W_a[128:256] into per-agent scalar ----
    {
        half8 ax[4], ah[4];
        #pragma unroll
        for (int k = 0; k < 4; ++k) {
            ax[k] = *(const half8*)&x_lds[l16][k * 32 + q * 8];
            ah[k] = *(const half8*)&h_lds[l16][k * 32 + q * 8];
        }
        float pa[4] = {0.f, 0.f, 0.f, 0.f};
        #pragma unroll
        for (int s = 0; s < 2; ++s) {
            const int colb = w * 32 + s * 16;
            f32x4 gi[3], gh[3];
            #pragma unroll
            for (int g = 0; g < 3; ++g) {
                const int n0 = g * 128 + colb;
                f32x4 ci = {0.f, 0.f, 0.f, 0.f}, ch = {0.f, 0.f, 0.f, 0.f};
                #pragma unroll
                for (int k = 0; k < 4; ++k) {
                    ci = MFMA(ax[k], ldB(wxT, 128, n0, k * 32, l), ci);
                    ch = MFMA(ah[k], ldB(whT, 128, n0, k * 32, l), ch);
                }
                gi[g] = ci; gh[g] = ch;
            }
            const int col = colb + l16;
            float bi0 = b_ih[col], bi1 = b_ih[HD + col], bi2 = b_ih[2 * HD + col];
            float bh0 = b_hh[col], bh1 = b_hh[HD + col], bh2 = b_hh[2 * HD + col];
            float wac = W_a[HD + col];
            #pragma unroll
            for (int r = 0; r < 4; ++r) {
                const int row = q * 4 + r;
                float rg = sigm(gi[0][r] + bi0 + gh[0][r] + bh0);
                float zg = sigm(gi[1][r] + bi1 + gh[1][r] + bh1);
                float ng = tanh_fast(gi[2][r] + bi2 + rg * (gh[2][r] + bh2));
                float hv = (1.f - zg) * ng + zg * (float)h_lds[row][col];
                out[QN + (size_t)(a0 + row) * HD + col] = hv;   // output 1: h_new
                hn_lds[row][col] = (half_t)hv;
                pa[r] = fmaf(hv, wac, pa[r]);
            }
        }
        #pragma unroll
        for (int r = 0; r < 4; ++r) {
            #pragma unroll
            for (int m = 1; m <= 8; m <<= 1) pa[r] += __shfl_xor(pa[r], m);
            if (l16 == 0) atomicAdd(&hnwa[q * 4 + r], pa[r]);
        }
    }
    __syncthreads();   // hn_lds + hnwa complete

    // ---- S4h: che = h_new @ We1h + b_e1 -> out q-rows (f16, over agg) ----
    {
        half8 an[4];
        #pragma unroll
        for (int k = 0; k < 4; ++k) an[k] = *(const half8*)&hn_lds[l16][k * 32 + q * 8];
        #pragma unroll
        for (int s = 0; s < 2; ++s) {
            const int n0 = (w * 2 + s) * 16;
            f32x4 c = {0.f, 0.f, 0.f, 0.f};
            #pragma unroll
            for (int k = 0; k < 4; ++k) c = MFMA(an[k], ldB(we1hT, 128, n0, k * 32, l), c);
            float bv = b_e1[n0 + l16];
            #pragma unroll
            for (int r = 0; r < 4; ++r) {
                half_t* arow_out = (half_t*)((char*)out + (size_t)(a0 + q * 4 + r) * QROWB);
                arow_out[n0 + l16] = (half_t)(c[r] + bv);
            }
        }
    }
    if (t < AGB) hn_wa_g[a0 + t] = hnwa[t];
}

// ====== K3: ze = relu([fn|ef]@We1e + che); q-values + agent scalar =========
__global__ __launch_bounds__(256, 2) void k_edge(
    const float* __restrict__ feat_nbr, const float* __restrict__ edge_feat,
    const float* __restrict__ W_e2, const float* __restrict__ b_e2,
    const float* __restrict__ W_a, const float* __restrict__ b_a,
    const int* __restrict__ src_idx, const half_t* __restrict__ ws,
    float* __restrict__ out)
{
    const int t = threadIdx.x;
    const int w = t >> 6, l = t & 63;
    const int l16 = l & 15, q = l >> 4;
    const int a0 = blockIdx.x * AGB;
    const int be = blockIdx.x * EPB;
    const half_t* we1eT = ws + O_WE1E;
    const float* hn_wa_g = (const float*)(ws + W_TOTAL);
    const half8 hz = {0, 0, 0, 0, 0, 0, 0, 0};

    __shared__ int srcs[EPB];
    srcs[t] = src_idx[be + t];
    __syncthreads();

    half8 B[4][4];
    float wa0[4], wa1[4];
    #pragma unroll
    for (int nc = 0; nc < 4; ++nc) {
        const int n0 = nc * 32;
        B[nc][0] = ldB(we1eT, 64, n0, 0, l);
        B[nc][1] = ldB(we1eT, 64, n0, 32, l);
        B[nc][2] = ldB(we1eT, 64, n0 + 16, 0, l);
        B[nc][3] = ldB(we1eT, 64, n0 + 16, 32, l);
        wa0[nc] = W_a[n0 + l16];
        wa1[nc] = W_a[n0 + 16 + l16];
    }
    const float ba = b_a[0];

    #pragma unroll
    for (int mt = 0; mt < 4; ++mt) {
        const int al = w * 4 + mt;
        const int arow = al * 16 + l16;
        const float* fr = feat_nbr + (size_t)srcs[arow] * 32 + q * 8;
        half8 af0 = cvt8(*(const float4*)fr, *(const float4*)(fr + 4));
        half8 af1 = hz;
        if (q == 0) {
            const float* er = edge_feat + (size_t)(be + arow) * 8;
            af1 = cvt8(*(const float4*)er, *(const float4*)(er + 4));
        }
        const half_t* che_row = (const half_t*)((const char*)out + (size_t)(a0 + al) * QROWB);
        float qa[4][4];
        #pragma unroll
        for (int r = 0; r < 4; ++r)
            #pragma unroll
            for (int p = 0; p < 4; ++p) qa[r][p] = 0.f;
        float wa_part = 0.f;
        #pragma unroll
        for (int nc = 0; nc < 4; ++nc) {
            const int n0 = nc * 32;
            f32x4 c0 = {0.f, 0.f, 0.f, 0.f}, c1 = {0.f, 0.f, 0.f, 0.f};
            c0 = MFMA(af0, B[nc][0], c0);
            c0 = MFMA(af1, B[nc][1], c0);
            c1 = MFMA(af0, B[nc][2], c1);
            c1 = MFMA(af1, B[nc][3], c1);
            const int col0 = n0 + l16, col1 = n0 + 16 + l16;
            float ch0 = (float)che_row[col0], ch1 = (float)che_row[col1];
            float4 w20 = *(const float4*)(W_e2 + col0 * 4);
            float4 w21 = *(const float4*)(W_e2 + col1 * 4);
            float s0 = 0.f, s1 = 0.f;
            #pragma unroll
            for (int r = 0; r < 4; ++r) {
                float z0 = fmaxf(c0[r] + ch0, 0.f);
                float z1 = fmaxf(c1[r] + ch1, 0.f);
                s0 += z0; s1 += z1;
                qa[r][0] = fmaf(z0, w20.x, fmaf(z1, w21.x, qa[r][0]));
                qa[r][1] = fmaf(z0, w20.y, fmaf(z1, w21.y, qa[r][1]));
                qa[r][2] = fmaf(z0, w20.z, fmaf(z1, w21.z, qa[r][2]));
                qa[r][3] = fmaf(z0, w20.w, fmaf(z1, w21.w, qa[r][3]));
            }
            s0 += __shfl_xor(s0, 16); s0 += __shfl_xor(s0, 32);
            s1 += __shfl_xor(s1, 16); s1 += __shfl_xor(s1, 32);
            wa_part = fmaf(s0, wa0[nc], fmaf(s1, wa1[nc], wa_part));
        }
        #pragma unroll
        for (int m = 1; m <= 8; m <<= 1)
            #pragma unroll
            for (int r = 0; r < 4; ++r)
                #pragma unroll
                for (int p = 0; p < 4; ++p) qa[r][p] += __shfl_xor(qa[r][p], m);
        if (l16 < 4) {
            const int p = l16;
            const float bz = b_e2[p];
            #pragma unroll
            for (int r = 0; r < 4; ++r)
                out[(size_t)(a0 + al) * QCOLS + (q * 4 + r) * 4 + p] = qa[r][p] + bz;
        }
        #pragma unroll
        for (int m = 1; m <= 8; m <<= 1) wa_part += __shfl_xor(wa_part, m);
        if (l == 0)
            out[(size_t)(a0 + al) * QCOLS + 64] = wa_part + hn_wa_g[a0 + al] + ba;
    }
}

extern "C" void kernel_launch(void* const* d_in, const int* in_sizes, int n_in,
                              void* d_out, int out_size, void* d_ws, size_t ws_size,
                              hipStream_t stream) {
    const float* feat_nbr   = (const float*)d_in[0];
    const float* feat_agent = (const float*)d_in[1];
    const float* edge_feat  = (const float*)d_in[2];
    const float* h_in       = (const float*)d_in[3];
    const float* W_msg = (const float*)d_in[4];
    const float* b_msg = (const float*)d_in[5];
    const float* W_upd = (const float*)d_in[6];
    const float* b_upd = (const float*)d_in[7];
    const float* W_x   = (const float*)d_in[8];
    const float* W_h   = (const float*)d_in[9];
    const float* b_ih  = (const float*)d_in[10];
    const float* b_hh  = (const float*)d_in[11];
    const float* W_e1  = (const float*)d_in[12];
    const float* b_e1  = (const float*)d_in[13];
    const float* W_e2  = (const float*)d_in[14];
    const float* b_e2  = (const float*)d_in[15];
    const float* W_a   = (const float*)d_in[16];
    const float* b_a   = (const float*)d_in[17];
    const int* src_idx = (const int*)d_in[18];
    // d_in[19] = dst_idx unused: edges grouped by dst, fixed degree 16.
    half_t* ws = (half_t*)d_ws;
    float* out = (float*)d_out;
    const int nblk = NAGENT / AGB;   // 2048

    prep_weights<<<(W_TOTAL + 255) / 256, 256, 0, stream>>>(W_msg, W_upd, W_x, W_h, W_e1, ws);
    k_msg<<<nblk, 256, 0, stream>>>(feat_nbr, edge_feat, b_msg, src_idx, ws, out);
    k_node<<<nblk, 256, 0, stream>>>(feat_agent, h_in, b_upd, b_ih, b_hh, b_e1, W_a, ws, out);
    k_edge<<<nblk, 256, 0, stream>>>(feat_nbr, edge_feat, W_e2, b_e2, W_a, b_a, src_idx, ws, out);
}